// Round 13
// baseline (669.749 us; speedup 1.0000x reference)
//
#include <hip/hip_runtime.h>
#include <math.h>

#define NG   2048
#define NN   48
#define FIN  64
#define HIDC 128
#define DEG  8
#define EPG  (NN*DEG)   // 384 edges per graph
#define NATT 8
#define KTOP 4
#define WPB  4          // waves (graphs) per block
#define NTH  (64*WPB)
#define OUTW (KTOP*HIDC + NATT)  // 520

// Per-wave (per-graph) LDS slab. One wave owns one graph; no __syncthreads
// anywhere — same-wave LDS ordering is guaranteed by lockstep execution +
// compiler-inserted lgkmcnt waits.
struct alignas(16) WS {
  float h[NN*HIDC];        // 24KB: activations; reused in-place (h -> messages -> h')
  float alpha[EPG];        // 1.5KB: edge alphas; reused as attn logits (48*8=384)
  int   row_start[NN+1];
  int   fill[NN];
  unsigned char csr[EPG];
};
static_assert(sizeof(WS) * WPB <= 160*1024, "LDS budget");

__device__ __forceinline__ float fast_tanh(float x) {
  // post-topk use only
  float e = __expf(2.f * x);
  return 1.f - 2.f * __builtin_amdgcn_rcpf(e + 1.f);
}

// One-wave GEMM: out[48][2cols] per lane (cols 2l,2l+1), h broadcast from LDS.
// acc[n] compile-time indexed (fully unrolled n-tiles).
template<int KD>
__device__ __forceinline__ void gemm1w(const float* __restrict__ hb,
                                       const float* __restrict__ Wg,
                                       int l, float2* acc) {
  const int c0 = 2*l;
  #pragma unroll
  for (int n = 0; n < NN; ++n) { acc[n].x = 0.f; acc[n].y = 0.f; }
  for (int kb = 0; kb < KD; kb += 4) {
    const float* wp = Wg + (size_t)kb*HIDC + c0;
    float2 w0 = *(const float2*)(wp);
    float2 w1 = *(const float2*)(wp + HIDC);
    float2 w2 = *(const float2*)(wp + 2*HIDC);
    float2 w3 = *(const float2*)(wp + 3*HIDC);
    #pragma unroll
    for (int nt = 0; nt < NN/8; ++nt) {
      float4 hv[8];
      #pragma unroll
      for (int j = 0; j < 8; ++j)
        hv[j] = *(const float4*)(hb + (nt*8 + j)*HIDC + kb);  // broadcast read
      #pragma unroll
      for (int j = 0; j < 8; ++j) {
        const int n = nt*8 + j;
        acc[n].x = fmaf(hv[j].x, w0.x, acc[n].x);
        acc[n].x = fmaf(hv[j].y, w1.x, acc[n].x);
        acc[n].x = fmaf(hv[j].z, w2.x, acc[n].x);
        acc[n].x = fmaf(hv[j].w, w3.x, acc[n].x);
        acc[n].y = fmaf(hv[j].x, w0.y, acc[n].y);
        acc[n].y = fmaf(hv[j].y, w1.y, acc[n].y);
        acc[n].y = fmaf(hv[j].z, w2.y, acc[n].y);
        acc[n].y = fmaf(hv[j].w, w3.y, acc[n].y);
      }
    }
  }
}

template<int KD, bool RELU>
__device__ __forceinline__ void layer1w(WS& w,
                                        const float* __restrict__ Wg,
                                        const float* __restrict__ avs,
                                        const float* __restrict__ avd,
                                        const float* __restrict__ bias,
                                        const float* __restrict__ lnw,
                                        const float* __restrict__ lnb,
                                        int l) {
  float2 acc[NN];
  gemm1w<KD>(w.h, Wg, l, acc);
  const int c0 = 2*l;
  float2 asv = *(const float2*)(avs + c0);
  float2 adv = *(const float2*)(avd + c0);
  // per-node attention scalars: butterfly per node; lane n keeps node n's
  float ssrc_o = 0.f, sdst_o = 0.f;
  #pragma unroll
  for (int n = 0; n < NN; ++n) {
    float ps = acc[n].x*asv.x + acc[n].y*asv.y;
    float pd = acc[n].x*adv.x + acc[n].y*adv.y;
    #pragma unroll
    for (int off = 32; off > 0; off >>= 1) {
      ps += __shfl_xor(ps, off, 64);
      pd += __shfl_xor(pd, off, 64);
    }
    if (l == n) { ssrc_o = ps; sdst_o = pd; }
  }
  // write messages over h (h fully consumed by gemm; same-wave order)
  #pragma unroll
  for (int n = 0; n < NN; ++n)
    *(float2*)(w.h + n*HIDC + c0) = acc[n];

  // edge softmax: lane n handles node n; shfl outside divergence
  const bool isn = l < NN;
  int b0 = 0, b1 = 0;
  if (isn) { b0 = w.row_start[l]; b1 = w.row_start[l+1]; }
  int deg = b1 - b0, maxdeg = deg;
  #pragma unroll
  for (int off = 32; off > 0; off >>= 1) maxdeg = max(maxdeg, __shfl_xor(maxdeg, off, 64));
  float es = ssrc_o + sdst_o; es = es > 0.f ? es : 0.2f*es;  // self loop
  float mx = es;
  for (int it = 0; it < maxdeg; ++it) {
    int q = b0 + it; bool v = isn && (q < b1);
    int src = v ? (int)w.csr[q] : 0;
    float sv = __shfl(ssrc_o, src, 64);    // all lanes execute
    float e = sv + sdst_o; e = e > 0.f ? e : 0.2f*e;
    if (v) { w.alpha[q] = e; mx = fmaxf(mx, e); }
  }
  float aself_o = 0.f;
  if (isn) {
    float pself = expf(es - mx);
    float z = pself;
    for (int q = b0; q < b1; ++q) { float p = expf(w.alpha[q] - mx); w.alpha[q] = p; z += p; }
    float inv = 1.f / (z + 1e-16f);
    aself_o = pself * inv;
    for (int q = b0; q < b1; ++q) w.alpha[q] *= inv;
  }

  // aggregation: lane-local columns; i unrolled so outv is compile-indexed
  float2 bcp = *(const float2*)(bias + c0);
  float2 outv[NN];
  #pragma unroll
  for (int i = 0; i < NN; ++i) {
    float asf = __shfl(aself_o, i, 64);
    float2 mi = *(const float2*)(w.h + i*HIDC + c0);
    float2 oi; oi.x = asf*mi.x; oi.y = asf*mi.y;
    int e0 = w.row_start[i], e1 = w.row_start[i+1];
    for (int q = e0; q < e1; ++q) {
      float a = w.alpha[q]; int sidx = (int)w.csr[q];
      float2 mm = *(const float2*)(w.h + sidx*HIDC + c0);
      oi.x = fmaf(a, mm.x, oi.x);
      oi.y = fmaf(a, mm.y, oi.y);
    }
    oi.x += bcp.x; oi.y += bcp.y;
    outv[i] = oi;
  }
  // graph-LN stats + apply; write h' back
  float lsum = 0.f, lsq = 0.f;
  #pragma unroll
  for (int i = 0; i < NN; ++i) {
    lsum += outv[i].x + outv[i].y;
    lsq = fmaf(outv[i].x, outv[i].x, lsq);
    lsq = fmaf(outv[i].y, outv[i].y, lsq);
  }
  #pragma unroll
  for (int off = 32; off > 0; off >>= 1) {
    lsum += __shfl_xor(lsum, off, 64);
    lsq  += __shfl_xor(lsq,  off, 64);
  }
  const float inv_n = 1.f / (NN*HIDC);
  float mu = lsum * inv_n;
  float rstd = 1.f / sqrtf(lsq * inv_n - mu*mu + 1e-5f);
  float2 wcp = *(const float2*)(lnw + c0);
  float2 bnp = *(const float2*)(lnb + c0);
  #pragma unroll
  for (int i = 0; i < NN; ++i) {
    float vx = (outv[i].x - mu)*rstd*wcp.x + bnp.x;
    float vy = (outv[i].y - mu)*rstd*wcp.y + bnp.y;
    if (RELU) { vx = fmaxf(vx, 0.f); vy = fmaxf(vy, 0.f); }
    *(float2*)(w.h + i*HIDC + c0) = make_float2(vx, vy);
  }
}

__global__ __launch_bounds__(NTH, 1)
void gat_wave(const float* __restrict__ x,
              const int* __restrict__ edge_src, const int* __restrict__ edge_dst,
              const float* __restrict__ W1, const float* __restrict__ as1, const float* __restrict__ ad1, const float* __restrict__ b1,
              const float* __restrict__ W2, const float* __restrict__ as2, const float* __restrict__ ad2, const float* __restrict__ b2,
              const float* __restrict__ W3, const float* __restrict__ as3, const float* __restrict__ ad3, const float* __restrict__ b3,
              const float* __restrict__ ln1w, const float* __restrict__ ln1b,
              const float* __restrict__ ln2w, const float* __restrict__ ln2b,
              const float* __restrict__ ln3w, const float* __restrict__ ln3b,
              const float* __restrict__ poolw,
              const float* __restrict__ fc1w, const float* __restrict__ fc1b,
              const float* __restrict__ fc2w, const float* __restrict__ fc2b,
              float* __restrict__ out) {
  __shared__ WS ws[WPB];
  const int tid = threadIdx.x, l = tid & 63, wid = tid >> 6;
  WS& w = ws[wid];
  const int g = blockIdx.x*WPB + wid;
  const int base = g * NN;
  const int c0 = 2*l;

  // stage x [48][64] into h rows (cols 0..63)
  {
    const float4* xs = (const float4*)(x + (size_t)base*FIN);
    #pragma unroll
    for (int j = 0; j < 12; ++j) {
      int idx = j*64 + l;            // float4 index in [0,768)
      float4 v = xs[idx];
      int n = idx >> 4;              // 16 float4 per 64-float row
      int k = (idx & 15) << 2;
      *(float4*)(w.h + n*HIDC + k) = v;
    }
  }

  // per-wave CSR build (LDS atomics within the wave's slab)
  if (l < NN) w.fill[l] = 0;
  const int* ed  = edge_dst + (size_t)g*EPG;
  const int* esp = edge_src + (size_t)g*EPG;
  #pragma unroll
  for (int j = 0; j < EPG/64; ++j)
    atomicAdd(&w.fill[ed[j*64 + l] - base], 1);
  {
    int cnt = (l < NN) ? w.fill[l] : 0;
    int xv = cnt;
    #pragma unroll
    for (int d = 1; d < 64; d <<= 1) {
      int v = __shfl_up(xv, d, 64);
      if (l >= d) xv += v;
    }
    if (l < NN) { w.row_start[l] = xv - cnt; w.fill[l] = xv - cnt; }
    if (l == NN-1) w.row_start[NN] = xv;
  }
  #pragma unroll
  for (int j = 0; j < EPG/64; ++j) {
    int e = j*64 + l;
    int d = ed[e] - base, sl2 = esp[e] - base;
    int pos = atomicAdd(&w.fill[d], 1);
    w.csr[pos] = (unsigned char)sl2;
  }

  layer1w<FIN,  true >(w, W1, as1, ad1, b1, ln1w, ln1b, l);
  layer1w<HIDC, true >(w, W2, as2, ad2, b2, ln2w, ln2b, l);
  layer1w<HIDC, false>(w, W3, as3, ad3, b3, ln3w, ln3b, l);

  // 1/||pool_w||
  float pw0 = poolw[c0], pw1 = poolw[c0+1];
  float nv = pw0*pw0 + pw1*pw1;
  #pragma unroll
  for (int off = 32; off > 0; off >>= 1) nv += __shfl_xor(nv, off, 64);
  float invnorm = 1.f / sqrtf(nv);

  // per-node score (precise tanhf) + rowsum; lane n keeps node n's
  float sc_o = -1e30f, rs_o = 0.f;
  #pragma unroll
  for (int n = 0; n < NN; ++n) {
    float2 hv = *(const float2*)(w.h + n*HIDC + c0);
    float d = hv.x*pw0 + hv.y*pw1;
    float r = hv.x + hv.y;
    #pragma unroll
    for (int off = 32; off > 0; off >>= 1) {
      d += __shfl_xor(d, off, 64);
      r += __shfl_xor(r, off, 64);
    }
    if (l == n) { sc_o = tanhf(d * invnorm); rs_o = r; }
  }

  // top-4 butterfly argmax (strict >, lowest index on tie)
  float cur = (l < NN) ? sc_o : -1e30f;
  float valk[KTOP]; int idxk[KTOP];
  #pragma unroll
  for (int k = 0; k < KTOP; ++k) {
    float bv = cur; int bi = l;
    #pragma unroll
    for (int d2 = 1; d2 < 64; d2 <<= 1) {
      float ov = __shfl_xor(bv, d2, 64);
      int   oi2 = __shfl_xor(bi, d2, 64);
      if (ov > bv || (ov == bv && oi2 < bi)) { bv = ov; bi = oi2; }
    }
    valk[k] = bv; idxk[k] = bi;
    if (l == bi) cur = -1e30f;
  }

  float* og = out + (size_t)g * OUTW;
  #pragma unroll
  for (int k = 0; k < KTOP; ++k) {
    float2 hv = *(const float2*)(w.h + idxk[k]*HIDC + c0);
    *(float2*)(og + k*HIDC + c0) = make_float2(hv.x*valk[k], hv.y*valk[k]);
  }

  // t = tanh(h @ fc1 + b) — kept entirely in registers
  float2 tacc[NN];
  gemm1w<HIDC>(w.h, fc1w, l, tacc);
  {
    float2 bv1 = *(const float2*)(fc1b + c0);
    #pragma unroll
    for (int n = 0; n < NN; ++n) {
      tacc[n].x = fast_tanh(tacc[n].x + bv1.x);
      tacc[n].y = fast_tanh(tacc[n].y + bv1.y);
    }
  }

  // logits[n][a] via butterflies; store to logits slab (reuse alpha)
  float f2a[NATT], f2b[NATT];
  #pragma unroll
  for (int a = 0; a < NATT; ++a) {
    f2a[a] = fc2w[(size_t)c0*NATT + a];
    f2b[a] = fc2w[(size_t)(c0+1)*NATT + a];
  }
  float* logits = w.alpha;
  #pragma unroll
  for (int nt = 0; nt < NN/8; ++nt) {
    float lg[8][NATT];
    #pragma unroll
    for (int j = 0; j < 8; ++j)
      #pragma unroll
      for (int a = 0; a < NATT; ++a)
        lg[j][a] = tacc[nt*8+j].x*f2a[a] + tacc[nt*8+j].y*f2b[a];
    #pragma unroll
    for (int j = 0; j < 8; ++j)
      #pragma unroll
      for (int a = 0; a < NATT; ++a) {
        float v = lg[j][a];
        #pragma unroll
        for (int off = 32; off > 0; off >>= 1) v += __shfl_xor(v, off, 64);
        if (l == j*8 + a) logits[(nt*8+j)*NATT + a] = v + fc2b[a];
      }
  }

  // head softmax over nodes + avg; all lanes execute (shfl), lanes 0..7 write
  {
    int a = l & 7;
    float m2 = -1e30f;
    for (int n = 0; n < NN; ++n) m2 = fmaxf(m2, logits[n*NATT + a]);
    float z2 = 0.f, acc2 = 0.f;
    for (int n = 0; n < NN; ++n) {
      float p = expf(logits[n*NATT + a] - m2);
      float rsv = __shfl(rs_o, n, 64);
      z2 += p; acc2 = fmaf(p, rsv, acc2);
    }
    if (l < NATT) og[KTOP*HIDC + a] = acc2 / z2 * (1.0f / NATT);
  }
}

extern "C" void kernel_launch(void* const* d_in, const int* in_sizes, int n_in,
                              void* d_out, int out_size, void* d_ws, size_t ws_size,
                              hipStream_t stream) {
  (void)in_sizes; (void)n_in; (void)d_ws; (void)ws_size; (void)out_size;
  const float* x    = (const float*)d_in[0];
  const int*   esrc = (const int*)  d_in[1];
  const int*   edst = (const int*)  d_in[2];
  // d_in[3] = batch (implicit in layout, unused)
  const float* W1   = (const float*)d_in[4];
  const float* as1  = (const float*)d_in[5];
  const float* ad1  = (const float*)d_in[6];
  const float* b1   = (const float*)d_in[7];
  const float* W2   = (const float*)d_in[8];
  const float* as2  = (const float*)d_in[9];
  const float* ad2  = (const float*)d_in[10];
  const float* b2   = (const float*)d_in[11];
  const float* W3   = (const float*)d_in[12];
  const float* as3  = (const float*)d_in[13];
  const float* ad3  = (const float*)d_in[14];
  const float* b3   = (const float*)d_in[15];
  const float* ln1w = (const float*)d_in[16];
  const float* ln1b = (const float*)d_in[17];
  const float* ln2w = (const float*)d_in[18];
  const float* ln2b = (const float*)d_in[19];
  const float* ln3w = (const float*)d_in[20];
  const float* ln3b = (const float*)d_in[21];
  const float* pw   = (const float*)d_in[22];
  const float* fc1w = (const float*)d_in[23];
  const float* fc1b = (const float*)d_in[24];
  const float* fc2w = (const float*)d_in[25];
  const float* fc2b = (const float*)d_in[26];
  float* out = (float*)d_out;

  gat_wave<<<NG/WPB, NTH, 0, stream>>>(x, esrc, edst,
                                       W1, as1, ad1, b1,
                                       W2, as2, ad2, b2,
                                       W3, as3, ad3, b3,
                                       ln1w, ln1b, ln2w, ln2b, ln3w, ln3b,
                                       pw, fc1w, fc1b, fc2w, fc2b, out);
}

// Round 15
// 307.524 us; speedup vs baseline: 2.1779x; 2.1779x over previous
//
#include <hip/hip_runtime.h>
#include <math.h>

#define NG   2048
#define NN   48
#define FIN  64
#define HIDC 128
#define DEG  8
#define EPG  (NN*DEG)   // 384 edges per graph
#define NATT 8
#define KTOP 4
#define NTH  256
#define OUTW (KTOP*HIDC + NATT)  // 520
#define NTOT (NG*NN)

__device__ __forceinline__ float fast_tanh(float x) {
  float e = __expf(2.f * x);
  return 1.f - 2.f * __builtin_amdgcn_rcpf(e + 1.f);
}

// R8 proven GEMM: 4-k software-pipelined W prefetch, acc[6][4]/thread.
// 256 threads = 32 cols(x4) x 8 rows(x6); h-reads are LDS broadcasts.
template<int KD>
__device__ __forceinline__ void gemm48(const float* in, const float* __restrict__ W,
                                       int t, float acc[6][4]) {
  const int col = t & 31, row = t >> 5;
  const int c0 = col * 4, n0 = row * 6;
  #pragma unroll
  for (int i = 0; i < 6; ++i)
    #pragma unroll
    for (int j = 0; j < 4; ++j) acc[i][j] = 0.f;
  const float* wp = W + c0;
  float4 w0 = *(const float4*)(wp + 0*HIDC);
  float4 w1 = *(const float4*)(wp + 1*HIDC);
  float4 w2 = *(const float4*)(wp + 2*HIDC);
  float4 w3 = *(const float4*)(wp + 3*HIDC);
  #pragma unroll 2
  for (int kb = 0; kb < KD - 4; kb += 4) {
    const float* np = wp + (size_t)(kb + 4) * HIDC;
    float4 nw0 = *(const float4*)(np + 0*HIDC);
    float4 nw1 = *(const float4*)(np + 1*HIDC);
    float4 nw2 = *(const float4*)(np + 2*HIDC);
    float4 nw3 = *(const float4*)(np + 3*HIDC);
    #pragma unroll
    for (int i = 0; i < 6; ++i) {
      float4 h = *(const float4*)(in + (n0+i)*KD + kb);
      acc[i][0] = fmaf(h.w, w3.x, fmaf(h.z, w2.x, fmaf(h.y, w1.x, fmaf(h.x, w0.x, acc[i][0]))));
      acc[i][1] = fmaf(h.w, w3.y, fmaf(h.z, w2.y, fmaf(h.y, w1.y, fmaf(h.x, w0.y, acc[i][1]))));
      acc[i][2] = fmaf(h.w, w3.z, fmaf(h.z, w2.z, fmaf(h.y, w1.z, fmaf(h.x, w0.z, acc[i][2]))));
      acc[i][3] = fmaf(h.w, w3.w, fmaf(h.z, w2.w, fmaf(h.y, w1.w, fmaf(h.x, w0.w, acc[i][3]))));
    }
    w0 = nw0; w1 = nw1; w2 = nw2; w3 = nw3;
  }
  {
    const int kb = KD - 4;
    #pragma unroll
    for (int i = 0; i < 6; ++i) {
      float4 h = *(const float4*)(in + (n0+i)*KD + kb);
      acc[i][0] = fmaf(h.w, w3.x, fmaf(h.z, w2.x, fmaf(h.y, w1.x, fmaf(h.x, w0.x, acc[i][0]))));
      acc[i][1] = fmaf(h.w, w3.y, fmaf(h.z, w2.y, fmaf(h.y, w1.y, fmaf(h.x, w0.y, acc[i][1]))));
      acc[i][2] = fmaf(h.w, w3.z, fmaf(h.z, w2.z, fmaf(h.y, w1.z, fmaf(h.x, w0.z, acc[i][2]))));
      acc[i][3] = fmaf(h.w, w3.w, fmaf(h.z, w2.w, fmaf(h.y, w1.w, fmaf(h.x, w0.w, acc[i][3]))));
    }
  }
}

// ------------------------- split-pipeline kernels -------------------------

__global__ __launch_bounds__(64)
void k_csr(const int* __restrict__ edge_src, const int* __restrict__ edge_dst,
           int* __restrict__ grs, unsigned char* __restrict__ gcsr) {
  __shared__ int fill[NN];
  __shared__ int rstart[NN+1];
  __shared__ unsigned char csr[EPG];
  const int g = blockIdx.x, l = threadIdx.x, base = g*NN;
  const int* ed = edge_dst + (size_t)g*EPG;
  const int* es = edge_src + (size_t)g*EPG;
  if (l < NN) fill[l] = 0;
  __syncthreads();
  #pragma unroll
  for (int j = 0; j < EPG/64; ++j) atomicAdd(&fill[ed[j*64 + l] - base], 1);
  __syncthreads();
  {
    int cnt = (l < NN) ? fill[l] : 0;
    int xv = cnt;
    #pragma unroll
    for (int d = 1; d < 64; d <<= 1) {
      int v = __shfl_up(xv, d, 64);
      if (l >= d) xv += v;
    }
    if (l < NN) { rstart[l] = xv - cnt; fill[l] = xv - cnt; }
    if (l == NN-1) rstart[NN] = xv;
  }
  __syncthreads();
  #pragma unroll
  for (int j = 0; j < EPG/64; ++j) {
    int e = j*64 + l;
    int pos = atomicAdd(&fill[ed[e] - base], 1);
    csr[pos] = (unsigned char)(es[e] - base);
  }
  __syncthreads();
  if (l < NN+1) grs[(size_t)g*(NN+1) + l] = rstart[l];
  // FIX (R14 bug): EPG/4 = 96 ints but only 64 threads -> strided loop
  for (int j = l; j < EPG/4; j += 64)
    ((int*)(gcsr + (size_t)g*EPG))[j] = ((const int*)csr)[j];
}

template<int KD>
__global__ __launch_bounds__(NTH)
void k_gemm(const float* __restrict__ hin, const float* __restrict__ W,
            const float* __restrict__ avs, const float* __restrict__ avd,
            float* __restrict__ msg, float* __restrict__ gss, float* __restrict__ gsd) {
  __shared__ float hs[NN*KD];
  const int g = blockIdx.x, t = threadIdx.x;
  {
    const float4* src = (const float4*)(hin + (size_t)g*NN*KD);
    float4* dst = (float4*)hs;
    #pragma unroll
    for (int j = 0; j < (NN*KD/4)/NTH; ++j) dst[j*NTH + t] = src[j*NTH + t];
  }
  __syncthreads();
  float acc[6][4];
  gemm48<KD>(hs, W, t, acc);
  const int col = t & 31, row = t >> 5, c0 = col*4, n0 = row*6;
  float4 asv = *(const float4*)(avs + c0);
  float4 adv = *(const float4*)(avd + c0);
  float* mg = msg + (size_t)g*NN*HIDC;
  #pragma unroll
  for (int i = 0; i < 6; ++i) {
    float4 v = make_float4(acc[i][0], acc[i][1], acc[i][2], acc[i][3]);
    *(float4*)(mg + (n0+i)*HIDC + c0) = v;
    float ps = v.x*asv.x + v.y*asv.y + v.z*asv.z + v.w*asv.w;
    float pd = v.x*adv.x + v.y*adv.y + v.z*adv.z + v.w*adv.w;
    #pragma unroll
    for (int off = 16; off > 0; off >>= 1) {
      ps += __shfl_xor(ps, off, 32);
      pd += __shfl_xor(pd, off, 32);
    }
    if (col == 0) {
      gss[(size_t)g*NN + n0+i] = ps;
      gsd[(size_t)g*NN + n0+i] = pd;
    }
  }
}

template<bool RELU>
__global__ __launch_bounds__(NTH)
void k_agg(const float* __restrict__ msg,
           const float* __restrict__ gss, const float* __restrict__ gsd,
           const int* __restrict__ grs, const unsigned char* __restrict__ gcsr,
           const float* __restrict__ bias,
           const float* __restrict__ lnw, const float* __restrict__ lnb,
           float* __restrict__ hout) {
  __shared__ struct alignas(16) {
    float m[NN*HIDC];        // 24KB
    float alpha[EPG];
    float ssrc[NN], sdst[NN], aself[NN];
    float red[16];
    int   row_start[NN+1];
    unsigned char csr[EPG];
  } s;
  const int g = blockIdx.x, t = threadIdx.x;
  {
    const float4* src = (const float4*)(msg + (size_t)g*NN*HIDC);
    float4* dst = (float4*)s.m;
    #pragma unroll
    for (int j = 0; j < (NN*HIDC/4)/NTH; ++j) dst[j*NTH + t] = src[j*NTH + t];
  }
  if (t < NN) { s.ssrc[t] = gss[(size_t)g*NN + t]; s.sdst[t] = gsd[(size_t)g*NN + t]; }
  if (t >= 64 && t < 64 + NN + 1) s.row_start[t-64] = grs[(size_t)g*(NN+1) + (t-64)];
  if (t >= 128 && t < 128 + EPG/4)
    ((int*)s.csr)[t-128] = ((const int*)(gcsr + (size_t)g*EPG))[t-128];
  __syncthreads();

  // parallel per-node softmax: 4 lanes per node (t < 192)
  if (t < 4*NN) {
    const int n = t >> 2, l = t & 3;
    const int b0 = s.row_start[n], b1 = s.row_start[n+1];
    const float di = s.sdst[n];
    float es = s.ssrc[n] + di; es = es > 0.f ? es : 0.2f*es;  // self loop
    float m = es;
    for (int q = b0 + l; q < b1; q += 4) {
      float e = s.ssrc[s.csr[q]] + di; e = e > 0.f ? e : 0.2f*e;
      s.alpha[q] = e;
      m = fmaxf(m, e);
    }
    m = fmaxf(m, __shfl_xor(m, 1, 4));
    m = fmaxf(m, __shfl_xor(m, 2, 4));
    float pself = expf(es - m);
    float z = (l == 0) ? pself : 0.f;
    for (int q = b0 + l; q < b1; q += 4) {
      float p = expf(s.alpha[q] - m); s.alpha[q] = p; z += p;
    }
    z += __shfl_xor(z, 1, 4);
    z += __shfl_xor(z, 2, 4);
    float inv = 1.f / (z + 1e-16f);
    for (int q = b0 + l; q < b1; q += 4) s.alpha[q] *= inv;
    if (l == 0) s.aself[n] = pself * inv;
  }
  __syncthreads();

  // aggregation: outputs held in registers across the LN-stats barrier
  const int cg = t & 31, rg = t >> 5;
  const float4 bc = *(const float4*)(bias + cg*4);
  const float4* hm4 = (const float4*)s.m;
  float4 av[6];
  float lsum = 0.f, lsq = 0.f;
  #pragma unroll
  for (int j = 0; j < 6; ++j) {
    const int i = rg + 8*j;
    const int b0 = s.row_start[i], b1 = s.row_start[i+1];
    float4 hv = hm4[i*32 + cg];
    const float asf = s.aself[i];
    float4 a4 = make_float4(asf*hv.x, asf*hv.y, asf*hv.z, asf*hv.w);
    int q = b0;
    float a_nxt = 0.f; int s_nxt = 0;
    if (q < b1) { a_nxt = s.alpha[q]; s_nxt = s.csr[q]; }
    while (q < b1) {
      const float a = a_nxt; const int sc = s_nxt;
      ++q;
      if (q < b1) { a_nxt = s.alpha[q]; s_nxt = s.csr[q]; }
      float4 h4 = hm4[sc*32 + cg];
      a4.x = fmaf(a, h4.x, a4.x);
      a4.y = fmaf(a, h4.y, a4.y);
      a4.z = fmaf(a, h4.z, a4.z);
      a4.w = fmaf(a, h4.w, a4.w);
    }
    a4.x += bc.x; a4.y += bc.y; a4.z += bc.z; a4.w += bc.w;
    av[j] = a4;
    lsum += a4.x + a4.y + a4.z + a4.w;
    lsq = fmaf(a4.x, a4.x, lsq); lsq = fmaf(a4.y, a4.y, lsq);
    lsq = fmaf(a4.z, a4.z, lsq); lsq = fmaf(a4.w, a4.w, lsq);
  }
  #pragma unroll
  for (int off = 32; off > 0; off >>= 1) {
    lsum += __shfl_xor(lsum, off, 64);
    lsq  += __shfl_xor(lsq,  off, 64);
  }
  const int wid = t >> 6;
  if ((t & 63) == 0) { s.red[wid] = lsum; s.red[8+wid] = lsq; }
  __syncthreads();
  {
    float su = s.red[0] + s.red[1] + s.red[2] + s.red[3];
    float sq = s.red[8] + s.red[9] + s.red[10] + s.red[11];
    const float inv_n = 1.f / (NN*HIDC);
    const float mu = su * inv_n;
    const float rstd = 1.f / sqrtf(sq * inv_n - mu*mu + 1e-5f);
    const float4 wc  = *(const float4*)(lnw + cg*4);
    const float4 bcn = *(const float4*)(lnb + cg*4);
    float4* ho = (float4*)(hout + (size_t)g*NN*HIDC);
    #pragma unroll
    for (int j = 0; j < 6; ++j) {
      const int i = rg + 8*j;
      float4 v = av[j];
      v.x = (v.x - mu)*rstd*wc.x + bcn.x;
      v.y = (v.y - mu)*rstd*wc.y + bcn.y;
      v.z = (v.z - mu)*rstd*wc.z + bcn.z;
      v.w = (v.w - mu)*rstd*wc.w + bcn.w;
      if (RELU) {
        v.x = fmaxf(v.x, 0.f); v.y = fmaxf(v.y, 0.f);
        v.z = fmaxf(v.z, 0.f); v.w = fmaxf(v.w, 0.f);
      }
      ho[i*32 + cg] = v;
    }
  }
}

__global__ __launch_bounds__(NTH)
void k_tail(const float* __restrict__ hbuf,
            const float* __restrict__ poolw,
            const float* __restrict__ fc1w, const float* __restrict__ fc1b,
            const float* __restrict__ fc2w, const float* __restrict__ fc2b,
            float* __restrict__ out) {
  __shared__ struct alignas(16) {
    float h[NN*HIDC];   // 24KB
    float tb[NN*HIDC];  // 24KB
    float logits[NN*NATT];
    float rs[NN], sc[NN];
    float valk[KTOP];
    int   idxk[KTOP];
  } s;
  const int g = blockIdx.x, t = threadIdx.x;
  {
    const float4* src = (const float4*)(hbuf + (size_t)g*NN*HIDC);
    float4* dst = (float4*)s.h;
    #pragma unroll
    for (int j = 0; j < (NN*HIDC/4)/NTH; ++j) dst[j*NTH + t] = src[j*NTH + t];
  }
  __syncthreads();

  float invnorm;
  {
    const int ln = t & 63;
    float p0 = poolw[ln], p1 = poolw[ln + 64];
    float v = p0*p0 + p1*p1;
    #pragma unroll
    for (int off = 32; off > 0; off >>= 1) v += __shfl_xor(v, off, 64);
    invnorm = 1.f / sqrtf(v);
  }
  {
    const int col = t & 31, row = t >> 5, n0 = row * 6;
    float pwv[4];
    #pragma unroll
    for (int q = 0; q < 4; ++q) pwv[q] = poolw[col + 32*q];
    #pragma unroll
    for (int i = 0; i < 6; ++i) {
      float d = 0.f, r = 0.f;
      #pragma unroll
      for (int q = 0; q < 4; ++q) {
        float v = s.h[(n0+i)*HIDC + col + 32*q];
        d = fmaf(v, pwv[q], d); r += v;
      }
      #pragma unroll
      for (int off = 16; off > 0; off >>= 1) {
        d += __shfl_xor(d, off, 32);
        r += __shfl_xor(r, off, 32);
      }
      if (col == 0) { s.sc[n0+i] = tanhf(d * invnorm); s.rs[n0+i] = r; }
    }
  }
  __syncthreads();

  if (t < 64) {
    float cur = (t < NN) ? s.sc[t] : -1e30f;
    #pragma unroll
    for (int k = 0; k < KTOP; ++k) {
      float bv = cur; int bi = t;
      #pragma unroll
      for (int d = 1; d < 64; d <<= 1) {
        float ov = __shfl_xor(bv, d, 64);
        int   oi = __shfl_xor(bi, d, 64);
        if (ov > bv || (ov == bv && oi < bi)) { bv = ov; bi = oi; }
      }
      if (t == 0) { s.valk[k] = bv; s.idxk[k] = bi; }
      if (t == bi) cur = -1e30f;
    }
  }
  __syncthreads();

  float* og = out + (size_t)g * OUTW;
  for (int o = t; o < KTOP*HIDC; o += NTH) {
    int k = o >> 7, c = o & 127;
    og[o] = s.h[s.idxk[k]*HIDC + c] * s.valk[k];
  }

  {
    float acc[6][4];
    gemm48<HIDC>(s.h, fc1w, t, acc);
    const int col = t & 31, row = t >> 5, c0 = col*4, n0 = row*6;
    float4 bv = *(const float4*)(fc1b + c0);
    #pragma unroll
    for (int i = 0; i < 6; ++i) {
      float4 v;
      v.x = fast_tanh(acc[i][0] + bv.x); v.y = fast_tanh(acc[i][1] + bv.y);
      v.z = fast_tanh(acc[i][2] + bv.z); v.w = fast_tanh(acc[i][3] + bv.w);
      *(float4*)(s.tb + (n0+i)*HIDC + c0) = v;
    }
  }
  __syncthreads();

  {
    const int col = t & 31, row = t >> 5, n0 = row * 6;
    #pragma unroll
    for (int i = 0; i < 6; ++i) {
      float lg[NATT];
      #pragma unroll
      for (int a = 0; a < NATT; ++a) lg[a] = 0.f;
      #pragma unroll
      for (int q = 0; q < 4; ++q) {
        float v = s.tb[(n0+i)*HIDC + col + 32*q];
        const float* f2 = fc2w + (size_t)(col + 32*q)*NATT;
        #pragma unroll
        for (int a = 0; a < NATT; ++a) lg[a] = fmaf(v, f2[a], lg[a]);
      }
      #pragma unroll
      for (int a = 0; a < NATT; ++a) {
        #pragma unroll
        for (int off = 16; off > 0; off >>= 1) lg[a] += __shfl_xor(lg[a], off, 32);
      }
      if (col == 0) {
        #pragma unroll
        for (int a = 0; a < NATT; ++a) s.logits[(n0+i)*NATT + a] = lg[a] + fc2b[a];
      }
    }
  }
  __syncthreads();

  {
    const int wv = t >> 6, ln = t & 63;
    #pragma unroll
    for (int aa = 0; aa < 2; ++aa) {
      const int a = wv + 4*aa;
      float lg = (ln < NN) ? s.logits[ln*NATT + a] : -1e30f;
      float m = lg;
      #pragma unroll
      for (int off = 32; off > 0; off >>= 1) m = fmaxf(m, __shfl_xor(m, off, 64));
      float p = (ln < NN) ? expf(lg - m) : 0.f;
      float w_n = (ln < NN) ? s.rs[ln] : 0.f;
      float zz = p, acc0 = p * w_n;
      #pragma unroll
      for (int off = 32; off > 0; off >>= 1) {
        zz   += __shfl_xor(zz,   off, 64);
        acc0 += __shfl_xor(acc0, off, 64);
      }
      if (ln == 0) og[KTOP*HIDC + a] = acc0 / zz * (1.0f / NATT);
    }
  }
}

// ------------------------- fused fallback (R8, 246us) -------------------------

struct alignas(16) SM {
  float hA[NN*HIDC];
  float hB[NN*HIDC];
  float alpha[EPG];
  float ssrc[NN], sdst[NN], aself[NN];
  float rs[NN], sc[NN];
  float red[16];
  float valk[KTOP];
  int   idxk[KTOP];
  int   row_start[NN+1];
  int   fill[NN];
  unsigned char csr_src[EPG];
};

template<int KD, bool RELU>
__device__ __forceinline__ void gat_layer(SM& s, const float* in, float* hmid, float* outbuf,
                                          const float* __restrict__ W,
                                          const float* __restrict__ avs,
                                          const float* __restrict__ avd,
                                          const float* __restrict__ bias,
                                          const float* __restrict__ lnw,
                                          const float* __restrict__ lnb, int t) {
  float acc[6][4];
  gemm48<KD>(in, W, t, acc);
  const int col = t & 31, row = t >> 5, c0 = col * 4, n0 = row * 6;
  float4 asv = *(const float4*)(avs + c0);
  float4 adv = *(const float4*)(avd + c0);
  #pragma unroll
  for (int i = 0; i < 6; ++i) {
    float4 v = make_float4(acc[i][0], acc[i][1], acc[i][2], acc[i][3]);
    *(float4*)(hmid + (n0+i)*HIDC + c0) = v;
    float ps = v.x*asv.x + v.y*asv.y + v.z*asv.z + v.w*asv.w;
    float pd = v.x*adv.x + v.y*adv.y + v.z*adv.z + v.w*adv.w;
    #pragma unroll
    for (int off = 16; off > 0; off >>= 1) {
      ps += __shfl_xor(ps, off, 32);
      pd += __shfl_xor(pd, off, 32);
    }
    if (col == 0) { s.ssrc[n0+i] = ps; s.sdst[n0+i] = pd; }
  }
  __syncthreads();
  if (t < 4*NN) {
    const int n = t >> 2, l = t & 3;
    const int b0 = s.row_start[n], b1 = s.row_start[n+1];
    const float di = s.sdst[n];
    float es = s.ssrc[n] + di; es = es > 0.f ? es : 0.2f*es;
    float m = es;
    for (int q = b0 + l; q < b1; q += 4) {
      float e = s.ssrc[s.csr_src[q]] + di; e = e > 0.f ? e : 0.2f*e;
      s.alpha[q] = e;
      m = fmaxf(m, e);
    }
    m = fmaxf(m, __shfl_xor(m, 1, 4));
    m = fmaxf(m, __shfl_xor(m, 2, 4));
    float pself = expf(es - m);
    float z = (l == 0) ? pself : 0.f;
    for (int q = b0 + l; q < b1; q += 4) {
      float p = expf(s.alpha[q] - m); s.alpha[q] = p; z += p;
    }
    z += __shfl_xor(z, 1, 4);
    z += __shfl_xor(z, 2, 4);
    float inv = 1.f / (z + 1e-16f);
    for (int q = b0 + l; q < b1; q += 4) s.alpha[q] *= inv;
    if (l == 0) s.aself[n] = pself * inv;
  }
  __syncthreads();
  {
    const int cg = t & 31, rg = t >> 5;
    const float4 bc = *(const float4*)(bias + cg*4);
    const float4* hm4 = (const float4*)hmid;
    float4* ob4 = (float4*)outbuf;
    float lsum = 0.f, lsq = 0.f;
    #pragma unroll
    for (int j = 0; j < 6; ++j) {
      const int i = rg + 8*j;
      const int b0 = s.row_start[i], b1 = s.row_start[i+1];
      float4 hv = hm4[i*32 + cg];
      const float asf = s.aself[i];
      float4 av = make_float4(asf*hv.x, asf*hv.y, asf*hv.z, asf*hv.w);
      int q = b0;
      float a_nxt = 0.f; int s_nxt = 0;
      if (q < b1) { a_nxt = s.alpha[q]; s_nxt = s.csr_src[q]; }
      while (q < b1) {
        const float a = a_nxt; const int sc = s_nxt;
        ++q;
        if (q < b1) { a_nxt = s.alpha[q]; s_nxt = s.csr_src[q]; }
        float4 h4 = hm4[sc*32 + cg];
        av.x = fmaf(a, h4.x, av.x);
        av.y = fmaf(a, h4.y, av.y);
        av.z = fmaf(a, h4.z, av.z);
        av.w = fmaf(a, h4.w, av.w);
      }
      av.x += bc.x; av.y += bc.y; av.z += bc.z; av.w += bc.w;
      ob4[i*32 + cg] = av;
      lsum += av.x + av.y + av.z + av.w;
      lsq = fmaf(av.x, av.x, lsq); lsq = fmaf(av.y, av.y, lsq);
      lsq = fmaf(av.z, av.z, lsq); lsq = fmaf(av.w, av.w, lsq);
    }
    #pragma unroll
    for (int off = 32; off > 0; off >>= 1) {
      lsum += __shfl_xor(lsum, off, 64);
      lsq  += __shfl_xor(lsq,  off, 64);
    }
    const int wid = t >> 6;
    if ((t & 63) == 0) { s.red[wid] = lsum; s.red[8+wid] = lsq; }
  }
  __syncthreads();
  {
    float su = s.red[0] + s.red[1] + s.red[2] + s.red[3];
    float sq = s.red[8] + s.red[9] + s.red[10] + s.red[11];
    const float inv_n = 1.f / (NN*HIDC);
    const float mu = su * inv_n;
    const float rstd = 1.f / sqrtf(sq * inv_n - mu*mu + 1e-5f);
    const int cg = t & 31;
    const float4 wc  = *(const float4*)(lnw + cg*4);
    const float4 bcn = *(const float4*)(lnb + cg*4);
    float4* ob4 = (float4*)outbuf;
    for (int e = t; e < NN*32; e += NTH) {
      float4 v = ob4[e];
      v.x = (v.x - mu)*rstd*wc.x + bcn.x;
      v.y = (v.y - mu)*rstd*wc.y + bcn.y;
      v.z = (v.z - mu)*rstd*wc.z + bcn.z;
      v.w = (v.w - mu)*rstd*wc.w + bcn.w;
      if (RELU) {
        v.x = fmaxf(v.x, 0.f); v.y = fmaxf(v.y, 0.f);
        v.z = fmaxf(v.z, 0.f); v.w = fmaxf(v.w, 0.f);
      }
      ob4[e] = v;
    }
  }
  __syncthreads();
}

__global__ __launch_bounds__(NTH)
void gat_fused(const float* __restrict__ x,
               const int* __restrict__ edge_src, const int* __restrict__ edge_dst,
               const float* __restrict__ W1, const float* __restrict__ as1, const float* __restrict__ ad1, const float* __restrict__ b1,
               const float* __restrict__ W2, const float* __restrict__ as2, const float* __restrict__ ad2, const float* __restrict__ b2,
               const float* __restrict__ W3, const float* __restrict__ as3, const float* __restrict__ ad3, const float* __restrict__ b3,
               const float* __restrict__ ln1w, const float* __restrict__ ln1b,
               const float* __restrict__ ln2w, const float* __restrict__ ln2b,
               const float* __restrict__ ln3w, const float* __restrict__ ln3b,
               const float* __restrict__ poolw,
               const float* __restrict__ fc1w, const float* __restrict__ fc1b,
               const float* __restrict__ fc2w, const float* __restrict__ fc2b,
               float* __restrict__ out) {
  __shared__ SM s;
  const int g = blockIdx.x, t = threadIdx.x;
  const int base = g * NN;
  {
    const float4* xs = (const float4*)(x + (size_t)base*FIN);
    for (int e = t; e < NN*FIN/4; e += NTH) ((float4*)s.hA)[e] = xs[e];
  }
  if (t < NN) s.fill[t] = 0;
  __syncthreads();
  for (int e = t; e < EPG; e += NTH)
    atomicAdd(&s.fill[edge_dst[(size_t)g*EPG + e] - base], 1);
  __syncthreads();
  if (t < 64) {
    int cnt = (t < NN) ? s.fill[t] : 0;
    int xv = cnt;
    #pragma unroll
    for (int d = 1; d < 64; d <<= 1) {
      int v = __shfl_up(xv, d, 64);
      if (t >= d) xv += v;
    }
    if (t < NN) { s.row_start[t] = xv - cnt; s.fill[t] = xv - cnt; }
    if (t == NN-1) s.row_start[NN] = xv;
  }
  __syncthreads();
  for (int e = t; e < EPG; e += NTH) {
    int d  = edge_dst[(size_t)g*EPG + e] - base;
    int sl = edge_src[(size_t)g*EPG + e] - base;
    int pos = atomicAdd(&s.fill[d], 1);
    s.csr_src[pos] = (unsigned char)sl;
  }
  __syncthreads();

  gat_layer<FIN,  true >(s, s.hA, s.hB, s.hA, W1, as1, ad1, b1, ln1w, ln1b, t);
  gat_layer<HIDC, true >(s, s.hA, s.hB, s.hA, W2, as2, ad2, b2, ln2w, ln2b, t);
  gat_layer<HIDC, false>(s, s.hA, s.hB, s.hA, W3, as3, ad3, b3, ln3w, ln3b, t);

  float invnorm;
  {
    const int ln = t & 63;
    float p0 = poolw[ln], p1 = poolw[ln + 64];
    float v = p0*p0 + p1*p1;
    #pragma unroll
    for (int off = 32; off > 0; off >>= 1) v += __shfl_xor(v, off, 64);
    invnorm = 1.f / sqrtf(v);
  }
  {
    const int col = t & 31, row = t >> 5, n0 = row * 6;
    float pwv[4];
    #pragma unroll
    for (int q = 0; q < 4; ++q) pwv[q] = poolw[col + 32*q];
    #pragma unroll
    for (int i = 0; i < 6; ++i) {
      float d = 0.f, r = 0.f;
      #pragma unroll
      for (int q = 0; q < 4; ++q) {
        float v = s.hA[(n0+i)*HIDC + col + 32*q];
        d = fmaf(v, pwv[q], d); r += v;
      }
      #pragma unroll
      for (int off = 16; off > 0; off >>= 1) {
        d += __shfl_xor(d, off, 32);
        r += __shfl_xor(r, off, 32);
      }
      if (col == 0) { s.sc[n0+i] = tanhf(d * invnorm); s.rs[n0+i] = r; }
    }
  }
  __syncthreads();
  if (t < 64) {
    float cur = (t < NN) ? s.sc[t] : -1e30f;
    #pragma unroll
    for (int k = 0; k < KTOP; ++k) {
      float bv = cur; int bi = t;
      #pragma unroll
      for (int d = 1; d < 64; d <<= 1) {
        float ov = __shfl_xor(bv, d, 64);
        int   oi = __shfl_xor(bi, d, 64);
        if (ov > bv || (ov == bv && oi < bi)) { bv = ov; bi = oi; }
      }
      if (t == 0) { s.valk[k] = bv; s.idxk[k] = bi; }
      if (t == bi) cur = -1e30f;
    }
  }
  __syncthreads();

  float* og = out + (size_t)g * OUTW;
  for (int o = t; o < KTOP*HIDC; o += NTH) {
    int k = o >> 7, c = o & 127;
    og[o] = s.hA[s.idxk[k]*HIDC + c] * s.valk[k];
  }
  {
    float acc[6][4];
    gemm48<HIDC>(s.hA, fc1w, t, acc);
    const int col = t & 31, row = t >> 5, c0 = col*4, n0 = row*6;
    float4 bv = *(const float4*)(fc1b + c0);
    #pragma unroll
    for (int i = 0; i < 6; ++i) {
      float4 v;
      v.x = fast_tanh(acc[i][0] + bv.x); v.y = fast_tanh(acc[i][1] + bv.y);
      v.z = fast_tanh(acc[i][2] + bv.z); v.w = fast_tanh(acc[i][3] + bv.w);
      *(float4*)(s.hB + (n0+i)*HIDC + c0) = v;
    }
  }
  __syncthreads();
  {
    const int col = t & 31, row = t >> 5, n0 = row * 6;
    #pragma unroll
    for (int i = 0; i < 6; ++i) {
      float lg[NATT];
      #pragma unroll
      for (int a = 0; a < NATT; ++a) lg[a] = 0.f;
      #pragma unroll
      for (int q = 0; q < 4; ++q) {
        float v = s.hB[(n0+i)*HIDC + col + 32*q];
        const float* f2 = fc2w + (size_t)(col + 32*q)*NATT;
        #pragma unroll
        for (int a = 0; a < NATT; ++a) lg[a] = fmaf(v, f2[a], lg[a]);
      }
      #pragma unroll
      for (int a = 0; a < NATT; ++a) {
        #pragma unroll
        for (int off = 16; off > 0; off >>= 1) lg[a] += __shfl_xor(lg[a], off, 32);
      }
      if (col == 0) {
        #pragma unroll
        for (int a = 0; a < NATT; ++a) s.alpha[(n0+i)*NATT + a] = lg[a] + fc2b[a];
      }
    }
  }
  __syncthreads();
  {
    const int wv = t >> 6, ln = t & 63;
    #pragma unroll
    for (int aa = 0; aa < 2; ++aa) {
      const int a = wv + 4*aa;
      float lg = (ln < NN) ? s.alpha[ln*NATT + a] : -1e30f;
      float m = lg;
      #pragma unroll
      for (int off = 32; off > 0; off >>= 1) m = fmaxf(m, __shfl_xor(m, off, 64));
      float p = (ln < NN) ? expf(lg - m) : 0.f;
      float w_n = (ln < NN) ? s.rs[ln] : 0.f;
      float zz = p, acc0 = p * w_n;
      #pragma unroll
      for (int off = 32; off > 0; off >>= 1) {
        zz   += __shfl_xor(zz,   off, 64);
        acc0 += __shfl_xor(acc0, off, 64);
      }
      if (ln == 0) og[KTOP*HIDC + a] = acc0 / zz * (1.0f / NATT);
    }
  }
}

extern "C" void kernel_launch(void* const* d_in, const int* in_sizes, int n_in,
                              void* d_out, int out_size, void* d_ws, size_t ws_size,
                              hipStream_t stream) {
  (void)in_sizes; (void)n_in; (void)out_size;
  const float* x    = (const float*)d_in[0];
  const int*   esrc = (const int*)  d_in[1];
  const int*   edst = (const int*)  d_in[2];
  const float* W1   = (const float*)d_in[4];
  const float* as1  = (const float*)d_in[5];
  const float* ad1  = (const float*)d_in[6];
  const float* b1   = (const float*)d_in[7];
  const float* W2   = (const float*)d_in[8];
  const float* as2  = (const float*)d_in[9];
  const float* ad2  = (const float*)d_in[10];
  const float* b2   = (const float*)d_in[11];
  const float* W3   = (const float*)d_in[12];
  const float* as3  = (const float*)d_in[13];
  const float* ad3  = (const float*)d_in[14];
  const float* b3   = (const float*)d_in[15];
  const float* ln1w = (const float*)d_in[16];
  const float* ln1b = (const float*)d_in[17];
  const float* ln2w = (const float*)d_in[18];
  const float* ln2b = (const float*)d_in[19];
  const float* ln3w = (const float*)d_in[20];
  const float* ln3b = (const float*)d_in[21];
  const float* pw   = (const float*)d_in[22];
  const float* fc1w = (const float*)d_in[23];
  const float* fc1b = (const float*)d_in[24];
  const float* fc2w = (const float*)d_in[25];
  const float* fc2b = (const float*)d_in[26];
  float* out = (float*)d_out;

  // workspace layout for the split pipeline
  const size_t n_msg = (size_t)NTOT*HIDC;            // 12.58M floats
  const size_t need = (2*n_msg + 2*(size_t)NTOT) * sizeof(float)
                    + (size_t)NG*(NN+1)*sizeof(int) + (size_t)NG*EPG + 256;
  if (ws_size >= need) {
    char* w = (char*)d_ws;
    float* msg  = (float*)w;                      w += n_msg*sizeof(float);
    float* hbuf = (float*)w;                      w += n_msg*sizeof(float);
    float* gss  = (float*)w;                      w += (size_t)NTOT*sizeof(float);
    float* gsd  = (float*)w;                      w += (size_t)NTOT*sizeof(float);
    int*   grs  = (int*)w;                        w += (size_t)NG*(NN+1)*sizeof(int);
    unsigned char* gcsr = (unsigned char*)w;

    k_csr<<<NG, 64, 0, stream>>>(esrc, edst, grs, gcsr);
    k_gemm<FIN ><<<NG, NTH, 0, stream>>>(x,    W1, as1, ad1, msg, gss, gsd);
    k_agg<true ><<<NG, NTH, 0, stream>>>(msg, gss, gsd, grs, gcsr, b1, ln1w, ln1b, hbuf);
    k_gemm<HIDC><<<NG, NTH, 0, stream>>>(hbuf, W2, as2, ad2, msg, gss, gsd);
    k_agg<true ><<<NG, NTH, 0, stream>>>(msg, gss, gsd, grs, gcsr, b2, ln2w, ln2b, hbuf);
    k_gemm<HIDC><<<NG, NTH, 0, stream>>>(hbuf, W3, as3, ad3, msg, gss, gsd);
    k_agg<false><<<NG, NTH, 0, stream>>>(msg, gss, gsd, grs, gcsr, b3, ln3w, ln3b, hbuf);
    k_tail<<<NG, NTH, 0, stream>>>(hbuf, pw, fc1w, fc1b, fc2w, fc2b, out);
  } else {
    gat_fused<<<NG, NTH, 0, stream>>>(x, esrc, edst,
                                      W1, as1, ad1, b1,
                                      W2, as2, ad2, b2,
                                      W3, as3, ad3, b3,
                                      ln1w, ln1b, ln2w, ln2b, ln3w, ln3b,
                                      pw, fc1w, fc1b, fc2w, fc2b, out);
  }
}

// Round 16
// 244.922 us; speedup vs baseline: 2.7345x; 1.2556x over previous
//
#include <hip/hip_runtime.h>
#include <math.h>

#define NG   2048
#define NN   48
#define FIN  64
#define HIDC 128
#define DEG  8
#define EPG  (NN*DEG)   // 384 edges per graph
#define NATT 8
#define KTOP 4
#define NTH  256
#define OUTW (KTOP*HIDC + NATT)  // 520

struct alignas(16) SM {
  float hA[NN*HIDC];        // 24KB
  float hB[NN*HIDC];        // 24KB message buffer (layers only)
  float alpha[EPG];         // per-edge alpha; reused as attn logits (48*8)
  float ssrc[NN], sdst[NN], aself[NN];
  float rs[NN], sc[NN];
  float red[16];
  float valk[KTOP];
  int   idxk[KTOP];
  int   row_start[NN+1];
  int   fill[NN];
  unsigned char csr_src[EPG];  // node ids < 48 fit in u8
};

__device__ __forceinline__ float fast_tanh(float x) {
  // post-topk use only: 1 - 2/(e^{2x}+1); saturates correctly at +/-1
  float e = __expf(2.f * x);
  return 1.f - 2.f * __builtin_amdgcn_rcpf(e + 1.f);
}

// R8 proven GEMM: 4-k software-pipelined W prefetch, acc[6][4]/thread.
// 256 threads = 32 cols(x4) x 8 rows(x6); h-reads are LDS broadcasts.
template<int KD>
__device__ __forceinline__ void gemm48(const float* in, const float* __restrict__ W,
                                       int t, float acc[6][4]) {
  const int col = t & 31, row = t >> 5;
  const int c0 = col * 4, n0 = row * 6;
  #pragma unroll
  for (int i = 0; i < 6; ++i)
    #pragma unroll
    for (int j = 0; j < 4; ++j) acc[i][j] = 0.f;
  const float* wp = W + c0;
  float4 w0 = *(const float4*)(wp + 0*HIDC);
  float4 w1 = *(const float4*)(wp + 1*HIDC);
  float4 w2 = *(const float4*)(wp + 2*HIDC);
  float4 w3 = *(const float4*)(wp + 3*HIDC);
  #pragma unroll 2
  for (int kb = 0; kb < KD - 4; kb += 4) {
    const float* np = wp + (size_t)(kb + 4) * HIDC;
    float4 nw0 = *(const float4*)(np + 0*HIDC);
    float4 nw1 = *(const float4*)(np + 1*HIDC);
    float4 nw2 = *(const float4*)(np + 2*HIDC);
    float4 nw3 = *(const float4*)(np + 3*HIDC);
    #pragma unroll
    for (int i = 0; i < 6; ++i) {
      float4 h = *(const float4*)(in + (n0+i)*KD + kb);
      acc[i][0] = fmaf(h.w, w3.x, fmaf(h.z, w2.x, fmaf(h.y, w1.x, fmaf(h.x, w0.x, acc[i][0]))));
      acc[i][1] = fmaf(h.w, w3.y, fmaf(h.z, w2.y, fmaf(h.y, w1.y, fmaf(h.x, w0.y, acc[i][1]))));
      acc[i][2] = fmaf(h.w, w3.z, fmaf(h.z, w2.z, fmaf(h.y, w1.z, fmaf(h.x, w0.z, acc[i][2]))));
      acc[i][3] = fmaf(h.w, w3.w, fmaf(h.z, w2.w, fmaf(h.y, w1.w, fmaf(h.x, w0.w, acc[i][3]))));
    }
    w0 = nw0; w1 = nw1; w2 = nw2; w3 = nw3;
  }
  {
    const int kb = KD - 4;
    #pragma unroll
    for (int i = 0; i < 6; ++i) {
      float4 h = *(const float4*)(in + (n0+i)*KD + kb);
      acc[i][0] = fmaf(h.w, w3.x, fmaf(h.z, w2.x, fmaf(h.y, w1.x, fmaf(h.x, w0.x, acc[i][0]))));
      acc[i][1] = fmaf(h.w, w3.y, fmaf(h.z, w2.y, fmaf(h.y, w1.y, fmaf(h.x, w0.y, acc[i][1]))));
      acc[i][2] = fmaf(h.w, w3.z, fmaf(h.z, w2.z, fmaf(h.y, w1.z, fmaf(h.x, w0.z, acc[i][2]))));
      acc[i][3] = fmaf(h.w, w3.w, fmaf(h.z, w2.w, fmaf(h.y, w1.w, fmaf(h.x, w0.w, acc[i][3]))));
    }
  }
}

template<int KD, bool RELU>
__device__ __forceinline__ void gat_layer(SM& s, const float* in, float* hmid, float* outbuf,
                                          const float* __restrict__ W,
                                          const float* __restrict__ avs,
                                          const float* __restrict__ avd,
                                          const float* __restrict__ bias,
                                          const float* __restrict__ lnw,
                                          const float* __restrict__ lnb, int t) {
  float acc[6][4];
  gemm48<KD>(in, W, t, acc);
  const int col = t & 31, row = t >> 5, c0 = col * 4, n0 = row * 6;
  // store messages + attention-scalar epilogue (free from live accumulators)
  float4 asv = *(const float4*)(avs + c0);
  float4 adv = *(const float4*)(avd + c0);
  #pragma unroll
  for (int i = 0; i < 6; ++i) {
    float4 v = make_float4(acc[i][0], acc[i][1], acc[i][2], acc[i][3]);
    *(float4*)(hmid + (n0+i)*HIDC + c0) = v;
    float ps = v.x*asv.x + v.y*asv.y + v.z*asv.z + v.w*asv.w;
    float pd = v.x*adv.x + v.y*adv.y + v.z*adv.z + v.w*adv.w;
    #pragma unroll
    for (int off = 16; off > 0; off >>= 1) {
      ps += __shfl_xor(ps, off, 32);
      pd += __shfl_xor(pd, off, 32);
    }
    if (col == 0) { s.ssrc[n0+i] = ps; s.sdst[n0+i] = pd; }
  }
  __syncthreads();

  // parallel per-node softmax: 4 lanes per node (t < 192)
  if (t < 4*NN) {
    const int n = t >> 2, l = t & 3;
    const int b0 = s.row_start[n], b1 = s.row_start[n+1];
    const float di = s.sdst[n];
    float es = s.ssrc[n] + di; es = es > 0.f ? es : 0.2f*es;  // self loop
    float m = es;
    for (int q = b0 + l; q < b1; q += 4) {
      float e = s.ssrc[s.csr_src[q]] + di; e = e > 0.f ? e : 0.2f*e;
      s.alpha[q] = e;
      m = fmaxf(m, e);
    }
    m = fmaxf(m, __shfl_xor(m, 1, 4));
    m = fmaxf(m, __shfl_xor(m, 2, 4));
    float pself = expf(es - m);
    float z = (l == 0) ? pself : 0.f;
    for (int q = b0 + l; q < b1; q += 4) {
      float p = expf(s.alpha[q] - m); s.alpha[q] = p; z += p;
    }
    z += __shfl_xor(z, 1, 4);
    z += __shfl_xor(z, 2, 4);
    float inv = 1.f / (z + 1e-16f);
    for (int q = b0 + l; q < b1; q += 4) s.alpha[q] *= inv;
    if (l == 0) s.aself[n] = pself * inv;
  }
  __syncthreads();

  // aggregation (+ bias), float4 over columns, fused LN statistics.
  {
    const int cg = t & 31, rg = t >> 5;
    const float4 bc = *(const float4*)(bias + cg*4);
    const float4* hm4 = (const float4*)hmid;
    float4* ob4 = (float4*)outbuf;
    float lsum = 0.f, lsq = 0.f;
    #pragma unroll
    for (int j = 0; j < 6; ++j) {
      const int i = rg + 8*j;
      const int b0 = s.row_start[i], b1 = s.row_start[i+1];
      float4 hv = hm4[i*32 + cg];
      const float asf = s.aself[i];
      float4 av = make_float4(asf*hv.x, asf*hv.y, asf*hv.z, asf*hv.w);
      int q = b0;
      float a_nxt = 0.f; int s_nxt = 0;
      if (q < b1) { a_nxt = s.alpha[q]; s_nxt = s.csr_src[q]; }
      while (q < b1) {
        const float a = a_nxt; const int sc = s_nxt;
        ++q;
        if (q < b1) { a_nxt = s.alpha[q]; s_nxt = s.csr_src[q]; }
        float4 h4 = hm4[sc*32 + cg];
        av.x = fmaf(a, h4.x, av.x);
        av.y = fmaf(a, h4.y, av.y);
        av.z = fmaf(a, h4.z, av.z);
        av.w = fmaf(a, h4.w, av.w);
      }
      av.x += bc.x; av.y += bc.y; av.z += bc.z; av.w += bc.w;
      ob4[i*32 + cg] = av;
      lsum += av.x + av.y + av.z + av.w;
      lsq = fmaf(av.x, av.x, lsq); lsq = fmaf(av.y, av.y, lsq);
      lsq = fmaf(av.z, av.z, lsq); lsq = fmaf(av.w, av.w, lsq);
    }
    #pragma unroll
    for (int off = 32; off > 0; off >>= 1) {
      lsum += __shfl_xor(lsum, off, 64);
      lsq  += __shfl_xor(lsq,  off, 64);
    }
    const int wid = t >> 6;
    if ((t & 63) == 0) { s.red[wid] = lsum; s.red[8+wid] = lsq; }
  }
  __syncthreads();

  // LN apply, float4; every thread computes mu/rstd redundantly
  {
    float su = s.red[0] + s.red[1] + s.red[2] + s.red[3];
    float sq = s.red[8] + s.red[9] + s.red[10] + s.red[11];
    const float inv_n = 1.f / (NN*HIDC);
    const float mu = su * inv_n;
    const float rstd = 1.f / sqrtf(sq * inv_n - mu*mu + 1e-5f);
    const int cg = t & 31;
    const float4 wc  = *(const float4*)(lnw + cg*4);
    const float4 bcn = *(const float4*)(lnb + cg*4);
    float4* ob4 = (float4*)outbuf;
    for (int e = t; e < NN*32; e += NTH) {
      float4 v = ob4[e];
      v.x = (v.x - mu)*rstd*wc.x + bcn.x;
      v.y = (v.y - mu)*rstd*wc.y + bcn.y;
      v.z = (v.z - mu)*rstd*wc.z + bcn.z;
      v.w = (v.w - mu)*rstd*wc.w + bcn.w;
      if (RELU) {
        v.x = fmaxf(v.x, 0.f); v.y = fmaxf(v.y, 0.f);
        v.z = fmaxf(v.z, 0.f); v.w = fmaxf(v.w, 0.f);
      }
      ob4[e] = v;
    }
  }
  __syncthreads();
}

__global__ __launch_bounds__(NTH)
void gat_fused(const float* __restrict__ x,
               const int* __restrict__ edge_src, const int* __restrict__ edge_dst,
               const float* __restrict__ W1, const float* __restrict__ as1, const float* __restrict__ ad1, const float* __restrict__ b1,
               const float* __restrict__ W2, const float* __restrict__ as2, const float* __restrict__ ad2, const float* __restrict__ b2,
               const float* __restrict__ W3, const float* __restrict__ as3, const float* __restrict__ ad3, const float* __restrict__ b3,
               const float* __restrict__ ln1w, const float* __restrict__ ln1b,
               const float* __restrict__ ln2w, const float* __restrict__ ln2b,
               const float* __restrict__ ln3w, const float* __restrict__ ln3b,
               const float* __restrict__ poolw,
               const float* __restrict__ fc1w, const float* __restrict__ fc1b,
               const float* __restrict__ fc2w, const float* __restrict__ fc2b,
               float* __restrict__ out) {
  __shared__ SM s;
  const int g = blockIdx.x, t = threadIdx.x;
  const int base = g * NN;

  // stage x [48][64] into hA (vectorized)
  {
    const float4* xs = (const float4*)(x + (size_t)base*FIN);
    for (int e = t; e < NN*FIN/4; e += NTH) ((float4*)s.hA)[e] = xs[e];
  }

  // build per-graph CSR (incoming lists) in LDS
  if (t < NN) s.fill[t] = 0;
  __syncthreads();
  for (int e = t; e < EPG; e += NTH)
    atomicAdd(&s.fill[edge_dst[(size_t)g*EPG + e] - base], 1);
  __syncthreads();
  if (t < 64) {  // wave-0 shuffle prefix scan
    int cnt = (t < NN) ? s.fill[t] : 0;
    int xv = cnt;
    #pragma unroll
    for (int d = 1; d < 64; d <<= 1) {
      int v = __shfl_up(xv, d, 64);
      if (t >= d) xv += v;
    }
    if (t < NN) { s.row_start[t] = xv - cnt; s.fill[t] = xv - cnt; }
    if (t == NN-1) s.row_start[NN] = xv;
  }
  __syncthreads();
  for (int e = t; e < EPG; e += NTH) {
    int d  = edge_dst[(size_t)g*EPG + e] - base;
    int sl = edge_src[(size_t)g*EPG + e] - base;
    int pos = atomicAdd(&s.fill[d], 1);
    s.csr_src[pos] = (unsigned char)sl;
  }
  __syncthreads();

  gat_layer<FIN,  true >(s, s.hA, s.hB, s.hA, W1, as1, ad1, b1, ln1w, ln1b, t);
  gat_layer<HIDC, true >(s, s.hA, s.hB, s.hA, W2, as2, ad2, b2, ln2w, ln2b, t);
  gat_layer<HIDC, false>(s, s.hA, s.hB, s.hA, W3, as3, ad3, b3, ln3w, ln3b, t);

  // 1/||pool_w|| — per-wave shuffle, no LDS, no barrier
  float invnorm;
  {
    const int ln = t & 63;
    float p0 = poolw[ln], p1 = poolw[ln + 64];
    float v = p0*p0 + p1*p1;
    #pragma unroll
    for (int off = 32; off > 0; off >>= 1) v += __shfl_xor(v, off, 64);
    invnorm = 1.f / sqrtf(v);
  }

  // scores tanh(h.w/||w||) and row sums of h  (precise tanhf: top-k values)
  {
    const int col = t & 31, row = t >> 5, n0 = row * 6;
    float pwv[4];
    #pragma unroll
    for (int q = 0; q < 4; ++q) pwv[q] = poolw[col + 32*q];
    #pragma unroll
    for (int i = 0; i < 6; ++i) {
      float d = 0.f, r = 0.f;
      #pragma unroll
      for (int q = 0; q < 4; ++q) {
        float v = s.hA[(n0+i)*HIDC + col + 32*q];
        d = fmaf(v, pwv[q], d); r += v;
      }
      #pragma unroll
      for (int off = 16; off > 0; off >>= 1) {
        d += __shfl_xor(d, off, 32);
        r += __shfl_xor(r, off, 32);
      }
      if (col == 0) { s.sc[n0+i] = tanhf(d * invnorm); s.rs[n0+i] = r; }
    }
  }
  __syncthreads();

  // top-4 via wave-0 shuffle argmax (strict >, lowest index on tie — lax.top_k order)
  if (t < 64) {
    float cur = (t < NN) ? s.sc[t] : -1e30f;
    #pragma unroll
    for (int k = 0; k < KTOP; ++k) {
      float bv = cur; int bi = t;
      #pragma unroll
      for (int d = 1; d < 64; d <<= 1) {
        float ov = __shfl_xor(bv, d, 64);
        int   oi = __shfl_xor(bi, d, 64);
        if (ov > bv || (ov == bv && oi < bi)) { bv = ov; bi = oi; }
      }
      if (t == 0) { s.valk[k] = bv; s.idxk[k] = bi; }
      if (t == bi) cur = -1e30f;
    }
  }
  __syncthreads();

  float* og = out + (size_t)g * OUTW;
  for (int o = t; o < KTOP*HIDC; o += NTH) {
    int k = o >> 7, c = o & 127;
    og[o] = s.hA[s.idxk[k]*HIDC + c] * s.valk[k];
  }

  // t = tanh(h @ fc1 + fc1_b) kept in REGISTERS; fc2 logits computed directly
  // from the accumulators (no hB round-trip, no extra barrier).
  {
    float acc[6][4];
    gemm48<HIDC>(s.hA, fc1w, t, acc);
    const int col = t & 31, row = t >> 5, c0 = col*4, n0 = row*6;
    float4 bv = *(const float4*)(fc1b + c0);
    #pragma unroll
    for (int i = 0; i < 6; ++i) {
      acc[i][0] = fast_tanh(acc[i][0] + bv.x);
      acc[i][1] = fast_tanh(acc[i][1] + bv.y);
      acc[i][2] = fast_tanh(acc[i][2] + bv.z);
      acc[i][3] = fast_tanh(acc[i][3] + bv.w);
    }
    // fc2 weights for our 4 columns: fc2w[(c0+j)*NATT + a]
    float f2[4][NATT];
    #pragma unroll
    for (int j = 0; j < 4; ++j) {
      float4 lo = *(const float4*)(fc2w + (size_t)(c0+j)*NATT);
      float4 hi = *(const float4*)(fc2w + (size_t)(c0+j)*NATT + 4);
      f2[j][0] = lo.x; f2[j][1] = lo.y; f2[j][2] = lo.z; f2[j][3] = lo.w;
      f2[j][4] = hi.x; f2[j][5] = hi.y; f2[j][6] = hi.z; f2[j][7] = hi.w;
    }
    #pragma unroll
    for (int i = 0; i < 6; ++i) {
      float lg[NATT];
      #pragma unroll
      for (int a = 0; a < NATT; ++a) {
        lg[a] = acc[i][0]*f2[0][a] + acc[i][1]*f2[1][a]
              + acc[i][2]*f2[2][a] + acc[i][3]*f2[3][a];
      }
      #pragma unroll
      for (int a = 0; a < NATT; ++a) {
        #pragma unroll
        for (int off = 16; off > 0; off >>= 1) lg[a] += __shfl_xor(lg[a], off, 32);
      }
      if (col == 0) {
        #pragma unroll
        for (int a = 0; a < NATT; ++a) s.alpha[(n0+i)*NATT + a] = lg[a] + fc2b[a];
      }
    }
  }
  __syncthreads();

  // head softmax over nodes, wave-parallel: wave w handles heads w and w+4
  {
    const int wv = t >> 6, ln = t & 63;
    #pragma unroll
    for (int aa = 0; aa < 2; ++aa) {
      const int a = wv + 4*aa;
      float lg = (ln < NN) ? s.alpha[ln*NATT + a] : -1e30f;
      float m = lg;
      #pragma unroll
      for (int off = 32; off > 0; off >>= 1) m = fmaxf(m, __shfl_xor(m, off, 64));
      float p = (ln < NN) ? expf(lg - m) : 0.f;
      float w_n = (ln < NN) ? s.rs[ln] : 0.f;
      float zz = p, acc0 = p * w_n;
      #pragma unroll
      for (int off = 32; off > 0; off >>= 1) {
        zz   += __shfl_xor(zz,   off, 64);
        acc0 += __shfl_xor(acc0, off, 64);
      }
      if (ln == 0) og[KTOP*HIDC + a] = acc0 / zz * (1.0f / NATT);
    }
  }
}

extern "C" void kernel_launch(void* const* d_in, const int* in_sizes, int n_in,
                              void* d_out, int out_size, void* d_ws, size_t ws_size,
                              hipStream_t stream) {
  (void)in_sizes; (void)n_in; (void)d_ws; (void)ws_size; (void)out_size;
  const float* x    = (const float*)d_in[0];
  const int*   esrc = (const int*)  d_in[1];
  const int*   edst = (const int*)  d_in[2];
  // d_in[3] = batch (implicit in layout, unused)
  const float* W1   = (const float*)d_in[4];
  const float* as1  = (const float*)d_in[5];
  const float* ad1  = (const float*)d_in[6];
  const float* b1   = (const float*)d_in[7];
  const float* W2   = (const float*)d_in[8];
  const float* as2  = (const float*)d_in[9];
  const float* ad2  = (const float*)d_in[10];
  const float* b2   = (const float*)d_in[11];
  const float* W3   = (const float*)d_in[12];
  const float* as3  = (const float*)d_in[13];
  const float* ad3  = (const float*)d_in[14];
  const float* b3   = (const float*)d_in[15];
  const float* ln1w = (const float*)d_in[16];
  const float* ln1b = (const float*)d_in[17];
  const float* ln2w = (const float*)d_in[18];
  const float* ln2b = (const float*)d_in[19];
  const float* ln3w = (const float*)d_in[20];
  const float* ln3b = (const float*)d_in[21];
  const float* pw   = (const float*)d_in[22];
  const float* fc1w = (const float*)d_in[23];
  const float* fc1b = (const float*)d_in[24];
  const float* fc2w = (const float*)d_in[25];
  const float* fc2b = (const float*)d_in[26];
  float* out = (float*)d_out;

  gat_fused<<<NG, NTH, 0, stream>>>(x, esrc, edst,
                                    W1, as1, ad1, b1,
                                    W2, as2, ad2, b2,
                                    W3, as3, ad3, b3,
                                    ln1w, ln1b, ln2w, ln2b, ln3w, ln3b,
                                    pw, fc1w, fc1b, fc2w, fc2b, out);
}